// Round 1
// 688.611 us; speedup vs baseline: 1.1569x; 1.1569x over previous
//
#include <hip/hip_runtime.h>

#define VOCAB_ROWS 50001
#define EMB 32
#define UNITS 16
#define GATES 48
#define BATCH 256
#define SEQ 4096

// ---------------- Phase 1: per-vocab projection table ----------------
// proj[v][j] = bias[0][j] + sum_e emb[v][e] * kernel[e][j]
__global__ __launch_bounds__(256) void proj_kernel(const float* __restrict__ emb,
                                                   const float* __restrict__ kern,
                                                   const float* __restrict__ bias,
                                                   float* __restrict__ proj) {
    int gid = blockIdx.x * 256 + threadIdx.x;
    if (gid >= VOCAB_ROWS * GATES) return;
    int v = gid / GATES;
    int j = gid - v * GATES;
    const float4* e4 = (const float4*)(emb + v * EMB);   // emb rows are 128B, 16B-aligned
    float acc = bias[j];
#pragma unroll
    for (int e = 0; e < EMB / 4; ++e) {
        float4 ev = e4[e];
        acc = fmaf(ev.x, kern[(4 * e + 0) * GATES + j], acc);
        acc = fmaf(ev.y, kern[(4 * e + 1) * GATES + j], acc);
        acc = fmaf(ev.z, kern[(4 * e + 2) * GATES + j], acc);
        acc = fmaf(ev.w, kern[(4 * e + 3) * GATES + j], acc);
    }
    proj[gid] = acc;
}

// ---------------- Phase 2: sequential GRU scan ----------------
__device__ __forceinline__ float sigf(float x) {
    float e = __expf(-x);
    return __builtin_amdgcn_rcpf(1.0f + e);
}

__device__ __forceinline__ float rdlane(float v, int l) {
    return __int_as_float(__builtin_amdgcn_readlane(__float_as_int(v), l));
}

// VALU cross-lane half-swaps (gfx950). Direction probed at runtime:
// helper returns, in lanes i<32 (resp. i<16 of each 32-half), the value of y
// from lane i+32 (resp. i+16). selB says which asm output carries it.
__device__ __forceinline__ float swap32_hi(float y, bool selB) {
    float a = y, b = y;
    asm("v_permlane32_swap_b32 %0, %1" : "+v"(a), "+v"(b));
    return selB ? b : a;
}
__device__ __forceinline__ float swap16_hi(float y, bool selB) {
    float a = y, b = y;
    asm("v_permlane16_swap_b32 %0, %1" : "+v"(a), "+v"(b));
    return selB ? b : a;
}

// Column-per-lane layout: lane j in [0,48) owns gate column j of the 16x48
// matvec (z: 0-15, r: 16-31, h: 32-47); lanes 48-63 mirror 32-47 (unused).
// h state lives in lanes 0-15 (z columns). Per step: 16 FMAs + 1 gather dword
// per lane + 3 permlane swaps, vs previous 48 FMAs + 3 loads.
__global__ __launch_bounds__(64) void gru_scan(const int* __restrict__ ids,
                                               const float* __restrict__ reck,
                                               const float* __restrict__ bias,
                                               const float* __restrict__ proj,
                                               float* __restrict__ out) {
    const int lane = threadIdx.x & 63;
    const int j    = (lane < 48) ? lane : lane - 16;   // owned gate column
    const int b    = blockIdx.x;                       // one batch row per wave
    const int* __restrict__ idrow = ids + (size_t)b * SEQ;

    // probe swap operand direction once (wave-uniform booleans)
    bool selB32, selB16;
    {
        float pa = (float)lane, pb = pa;
        asm("v_permlane32_swap_b32 %0, %1" : "+v"(pa), "+v"(pb));
        selB32 = (rdlane(pb, 0) == 32.0f);
        float qa = (float)lane, qb = qa;
        asm("v_permlane16_swap_b32 %0, %1" : "+v"(qa), "+v"(qb));
        selB16 = (rdlane(qb, 0) == 16.0f);
    }

    // recurrent weight column j (16-deep) + recurrent bias
    float R[UNITS];
#pragma unroll
    for (int k = 0; k < UNITS; ++k) R[k] = reck[k * GATES + j];
    const float bj = bias[GATES + j];
    const unsigned offv = (unsigned)j;                 // word offset in proj row

    // software-pipeline rings: x column 8 ahead, ids 16 ahead
    float xq[8];
    int   idq[8];
#pragma unroll
    for (int s = 0; s < 8; ++s) {
        int id0 = idrow[s];
        xq[s]  = proj[(unsigned)(id0 * GATES) + offv];
        idq[s] = idrow[8 + s];
    }

    float h = 0.0f;                                    // valid in lanes 0-15
    for (int t0 = 0; t0 < SEQ; t0 += 8) {
#pragma unroll
        for (int uu = 0; uu < 8; ++uu) {
            const int t = t0 + uu;
            const float x = xq[uu];                    // lane j's proj value (has input bias)
            // prefetch: row for t+8 (id loaded 8 steps ago), id for t+16
            const int id8 = idq[uu];
            int tf = t + 16;
            tf = tf < SEQ ? tf : SEQ - 1;
            idq[uu] = idrow[tf];
            xq[uu]  = proj[(unsigned)(id8 * GATES) + offv];

            // a_j = b1[j] + sum_k R[k][j] * h[k]   (h broadcast via readlane/SGPR)
            float aa = bj, ab = 0.0f;
#pragma unroll
            for (int k = 0; k < 8; ++k) {
                const float ha = rdlane(h, k);
                const float hb = rdlane(h, k + 8);
                aa = fmaf(R[k],     ha, aa);
                ab = fmaf(R[k + 8], hb, ab);
            }
            const float a = aa + ab;
            const float y = sigf(x + a);               // z (lanes 0-15), r (16-31)

            // deliver r, rh(=a_h incl bias), xh into lanes 0-15 (VALU swaps)
            const float rt = swap16_hi(y, selB16);     // r from lane+16
            const float at = swap32_hi(a, selB32);     // recurrent h-part from lane+32
            const float xt = swap32_hi(x, selB32);     // xh from lane+32

            const float hh = sigf(fmaf(rt, at, xt));   // sigmoid(xh + r*rh)
            h = fmaf(y, h - hh, hh);                   // z*h + (1-z)*hh  (z = y, lanes 0-15)
        }
    }

    if (lane < UNITS) out[b * UNITS + lane] = h;
}

extern "C" void kernel_launch(void* const* d_in, const int* in_sizes, int n_in,
                              void* d_out, int out_size, void* d_ws, size_t ws_size,
                              hipStream_t stream) {
    const int*   ids  = (const int*)d_in[0];
    const float* emb  = (const float*)d_in[1];
    const float* kern = (const float*)d_in[2];
    const float* reck = (const float*)d_in[3];
    const float* bias = (const float*)d_in[4];
    float* out  = (float*)d_out;
    float* proj = (float*)d_ws;   // 50001*48 floats = 9.6 MB scratch

    const int total = VOCAB_ROWS * GATES;
    proj_kernel<<<(total + 255) / 256, 256, 0, stream>>>(emb, kern, bias, proj);
    gru_scan<<<BATCH, 64, 0, stream>>>(ids, reck, bias, proj, out);
}

// Round 3
// 686.838 us; speedup vs baseline: 1.1599x; 1.0026x over previous
//
#include <hip/hip_runtime.h>

#define VOCAB_ROWS 50001
#define EMB 32
#define UNITS 16
#define GATES 48
#define BATCH 256
#define SEQ 4096

// ---------------- Phase 1: per-vocab projection table ----------------
// proj[v][j] = bias[0][j] + sum_e emb[v][e] * kernel[e][j]
__global__ __launch_bounds__(256) void proj_kernel(const float* __restrict__ emb,
                                                   const float* __restrict__ kern,
                                                   const float* __restrict__ bias,
                                                   float* __restrict__ proj) {
    int gid = blockIdx.x * 256 + threadIdx.x;
    if (gid >= VOCAB_ROWS * GATES) return;
    int v = gid / GATES;
    int j = gid - v * GATES;
    const float4* e4 = (const float4*)(emb + v * EMB);   // emb rows are 128B, 16B-aligned
    float acc = bias[j];
#pragma unroll
    for (int e = 0; e < EMB / 4; ++e) {
        float4 ev = e4[e];
        acc = fmaf(ev.x, kern[(4 * e + 0) * GATES + j], acc);
        acc = fmaf(ev.y, kern[(4 * e + 1) * GATES + j], acc);
        acc = fmaf(ev.z, kern[(4 * e + 2) * GATES + j], acc);
        acc = fmaf(ev.w, kern[(4 * e + 3) * GATES + j], acc);
    }
    proj[gid] = acc;
}

// ---------------- Phase 2: sequential GRU scan ----------------
__device__ __forceinline__ float sigf(float x) {
    float e = __expf(-x);
    return __builtin_amdgcn_rcpf(1.0f + e);
}

__device__ __forceinline__ float rdlane(float v, int l) {
    return __int_as_float(__builtin_amdgcn_readlane(__float_as_int(v), l));
}

// VALU cross-lane half-swaps (gfx950). Direction probed at runtime once;
// selB (wave-uniform) picks which asm output carries hi-half -> lo-lanes.
__device__ __forceinline__ float swap32_hi(float y, bool selB) {
    float a = y, b = y;
    asm("v_permlane32_swap_b32 %0, %1" : "+v"(a), "+v"(b));
    return selB ? b : a;
}
__device__ __forceinline__ float swap16_hi(float y, bool selB) {
    float a = y, b = y;
    asm("v_permlane16_swap_b32 %0, %1" : "+v"(a), "+v"(b));
    return selB ? b : a;
}

// Column-per-lane layout: lane j in [0,48) owns gate column j of the 16x48
// matvec (z: 0-15, r: 16-31, h: 32-47); lanes 48-63 mirror 32-47.
// h state lives in lanes 0-15. Per step: 16 readlane + 16 FMA + 1 gather.
//
// __launch_bounds__(64, 1): we intentionally run 1 wave/block, 1 block/CU-
// quadrant; min-1-wave/EU tells regalloc to use the full VGPR file. Round-1
// build chose 24 VGPRs (< the ~33 live values: R[16]+xq[8]+idq[8]+h) and
// rematerialized the loop-invariant R[] weight loads inside the serial loop.
__global__ __launch_bounds__(64, 1) void gru_scan(const int* __restrict__ ids,
                                                  const float* __restrict__ reck,
                                                  const float* __restrict__ bias,
                                                  const float* __restrict__ proj,
                                                  float* __restrict__ out) {
    const int lane = threadIdx.x & 63;
    const int j    = (lane < 48) ? lane : lane - 16;   // owned gate column
    const int b    = blockIdx.x;                       // one batch row per wave
    const int* __restrict__ idrow = ids + (size_t)b * SEQ;

    // probe swap operand direction once (wave-uniform booleans)
    bool selB32, selB16;
    {
        float pa = (float)lane, pb = pa;
        asm("v_permlane32_swap_b32 %0, %1" : "+v"(pa), "+v"(pb));
        selB32 = (rdlane(pb, 0) == 32.0f);
        float qa = (float)lane, qb = qa;
        asm("v_permlane16_swap_b32 %0, %1" : "+v"(qa), "+v"(qb));
        selB16 = (rdlane(qb, 0) == 16.0f);
    }

    // recurrent weight column j (16-deep) + recurrent bias
    float R[UNITS];
#pragma unroll
    for (int k = 0; k < UNITS; ++k) R[k] = reck[k * GATES + j];
    const float bj = bias[GATES + j];
    const unsigned offv = (unsigned)j;                 // word offset in proj row

    // software-pipeline rings: x column 8 ahead, ids 16 ahead
    float xq[8];
    int   idq[8];
#pragma unroll
    for (int s = 0; s < 8; ++s) {
        int id0 = idrow[s];
        xq[s]  = proj[(unsigned)(id0 * GATES) + offv];
        idq[s] = idrow[8 + s];
    }

    float h = 0.0f;                                    // valid in lanes 0-15
    for (int t0 = 0; t0 < SEQ; t0 += 8) {
#pragma unroll
        for (int uu = 0; uu < 8; ++uu) {
            const int t = t0 + uu;
            const float x = xq[uu];                    // lane j's proj value (has input bias)
            // prefetch: row for t+8 (id loaded 8 steps ago), id for t+16
            const int id8 = idq[uu];
            int tf = t + 16;
            tf = tf < SEQ ? tf : SEQ - 1;
            idq[uu] = idrow[tf];
            xq[uu]  = proj[(unsigned)(id8 * GATES) + offv];

            // a_j = b1[j] + sum_k R[k][j] * h[k]   (h broadcast via readlane/SGPR)
            float aa = bj, ab = 0.0f;
#pragma unroll
            for (int k = 0; k < 8; ++k) {
                const float ha = rdlane(h, k);
                const float hb = rdlane(h, k + 8);
                aa = fmaf(R[k],     ha, aa);
                ab = fmaf(R[k + 8], hb, ab);
            }
            const float a = aa + ab;
            const float y = sigf(x + a);               // z (lanes 0-15), r (16-31)

            // deliver r, ah(=recurrent h incl bias), xh into lanes 0-15
            const float rt = swap16_hi(y, selB16);     // r from lane+16
            const float at = swap32_hi(a, selB32);     // recurrent h-part from lane+32
            const float xt = swap32_hi(x, selB32);     // xh from lane+32

            const float hh = sigf(fmaf(rt, at, xt));   // sigmoid(xh + r*rh)
            h = fmaf(y, h - hh, hh);                   // z*h + (1-z)*hh
        }
    }

    if (lane < UNITS) out[b * UNITS + lane] = h;
}

extern "C" void kernel_launch(void* const* d_in, const int* in_sizes, int n_in,
                              void* d_out, int out_size, void* d_ws, size_t ws_size,
                              hipStream_t stream) {
    const int*   ids  = (const int*)d_in[0];
    const float* emb  = (const float*)d_in[1];
    const float* kern = (const float*)d_in[2];
    const float* reck = (const float*)d_in[3];
    const float* bias = (const float*)d_in[4];
    float* out  = (float*)d_out;
    float* proj = (float*)d_ws;   // 50001*48 floats = 9.6 MB scratch

    const int total = VOCAB_ROWS * GATES;
    proj_kernel<<<(total + 255) / 256, 256, 0, stream>>>(emb, kern, bias, proj);
    gru_scan<<<BATCH, 64, 0, stream>>>(ids, reck, bias, proj, out);
}